// Round 1
// baseline (15.911 us; speedup 1.0000x reference)
//
#include <hip/hip_runtime.h>

// ROI bilinear pooling: img (1,1024,1024,128) f32, rois (1,512,4) f32 [x1,y1,w,h]
// out (1,512,7,7,128) f32.
// TF1 resize_images bilinear align_corners=False: src = dst * size/POOL.

#define POOL 7
#define NUM_ROIS 512
#define IMG_H 1024
#define IMG_W 1024
#define IMG_C 128

__global__ __launch_bounds__(256) void roi_pool_kernel(
    const float* __restrict__ img,
    const float* __restrict__ rois,
    float* __restrict__ out)
{
    // One thread = one float4 (4 channels) of one (roi, py, px) position.
    // 32 consecutive lanes cover the 128 channels of one position -> coalesced.
    const int total = NUM_ROIS * POOL * POOL * 32;
    int idx = blockIdx.x * blockDim.x + threadIdx.x;
    if (idx >= total) return;

    const int c4  = idx & 31;        // which float4 within channel dim
    const int p   = idx >> 5;        // roi*49 + py*7 + px
    const int px  = p % POOL;
    const int t   = p / POOL;
    const int py  = t % POOL;
    const int roi = t / POOL;

    const float* r = rois + (size_t)roi * 4;
    const int x1 = (int)r[0];
    const int y1 = (int)r[1];
    const int w  = (int)r[2];
    const int h  = (int)r[3];

    // --- y axis coords (match reference float32 arithmetic exactly) ---
    const float scy = (float)h / 7.0f;
    const float sy  = (float)py * scy;
    int ylo = (int)floorf(sy);
    ylo = min(max(ylo, 0), h - 1);
    const int yhi = min(max(ylo + 1, 0), h - 1);
    const float fy = sy - (float)ylo;
    const int ylo_abs = min(max(y1 + ylo, 0), IMG_H - 1);
    const int yhi_abs = min(max(y1 + yhi, 0), IMG_H - 1);

    // --- x axis coords ---
    const float scx = (float)w / 7.0f;
    const float sx  = (float)px * scx;
    int xlo = (int)floorf(sx);
    xlo = min(max(xlo, 0), w - 1);
    const int xhi = min(max(xlo + 1, 0), w - 1);
    const float fx = sx - (float)xlo;
    const int xlo_abs = min(max(x1 + xlo, 0), IMG_W - 1);
    const int xhi_abs = min(max(x1 + xhi, 0), IMG_W - 1);

    const int coff = c4 * 4;
    const size_t b00 = ((size_t)ylo_abs * IMG_W + xlo_abs) * IMG_C + coff;
    const size_t b01 = ((size_t)ylo_abs * IMG_W + xhi_abs) * IMG_C + coff;
    const size_t b10 = ((size_t)yhi_abs * IMG_W + xlo_abs) * IMG_C + coff;
    const size_t b11 = ((size_t)yhi_abs * IMG_W + xhi_abs) * IMG_C + coff;

    const float4 v00 = *(const float4*)(img + b00);
    const float4 v01 = *(const float4*)(img + b01);
    const float4 v10 = *(const float4*)(img + b10);
    const float4 v11 = *(const float4*)(img + b11);

    const float gx = 1.0f - fx;
    const float gy = 1.0f - fy;

    float4 o;
    o.x = (v00.x * gx + v01.x * fx) * gy + (v10.x * gx + v11.x * fx) * fy;
    o.y = (v00.y * gx + v01.y * fx) * gy + (v10.y * gx + v11.y * fx) * fy;
    o.z = (v00.z * gx + v01.z * fx) * gy + (v10.z * gx + v11.z * fx) * fy;
    o.w = (v00.w * gx + v01.w * fx) * gy + (v10.w * gx + v11.w * fx) * fy;

    *(float4*)(out + (size_t)p * IMG_C + coff) = o;
}

extern "C" void kernel_launch(void* const* d_in, const int* in_sizes, int n_in,
                              void* d_out, int out_size, void* d_ws, size_t ws_size,
                              hipStream_t stream) {
    const float* img  = (const float*)d_in[0];
    const float* rois = (const float*)d_in[1];
    float* out = (float*)d_out;

    const int total = NUM_ROIS * POOL * POOL * 32;  // 802816 threads
    const int block = 256;
    const int grid  = (total + block - 1) / block;  // 3136 blocks
    roi_pool_kernel<<<grid, block, 0, stream>>>(img, rois, out);
}

// Round 2
// 15.659 us; speedup vs baseline: 1.0161x; 1.0161x over previous
//
#include <hip/hip_runtime.h>

// ROI bilinear pooling: img (1,1024,1024,128) f32, rois (1,512,4) f32 [x1,y1,w,h]
// out (1,512,7,7,128) f32.
// TF1 resize_images bilinear align_corners=False: src = dst * size/POOL.
// Each thread: one float4 channel slice of TWO (roi,py,px) positions
// (p and p + NPOS/2) -> 8 outstanding 512B-coalesced loads per thread.

#define POOL 7
#define NUM_ROIS 512
#define IMG_H 1024
#define IMG_W 1024
#define IMG_C 128
#define NPOS (NUM_ROIS * POOL * POOL)   // 25088
#define HALF (NPOS / 2)                 // 12544

struct Coords {
    size_t b00, b01, b10, b11;
    float fx, fy;
};

__device__ __forceinline__ Coords pos_coords(const float* __restrict__ rois,
                                             int p, int coff) {
    const int px  = p % POOL;
    const int t   = p / POOL;
    const int py  = t % POOL;
    const int roi = t / POOL;

    const float* r = rois + (size_t)roi * 4;
    const int x1 = (int)r[0];
    const int y1 = (int)r[1];
    const int w  = (int)r[2];
    const int h  = (int)r[3];

    // y axis (src >= 0, so int truncation == floor; matches reference fp32 math)
    const float scy = (float)h / 7.0f;
    const float sy  = (float)py * scy;
    int ylo = (int)sy;
    ylo = min(ylo, h - 1);
    const int yhi = min(ylo + 1, h - 1);
    const int ylo_abs = min(max(y1 + ylo, 0), IMG_H - 1);
    const int yhi_abs = min(max(y1 + yhi, 0), IMG_H - 1);

    // x axis
    const float scx = (float)w / 7.0f;
    const float sx  = (float)px * scx;
    int xlo = (int)sx;
    xlo = min(xlo, w - 1);
    const int xhi = min(xlo + 1, w - 1);
    const int xlo_abs = min(max(x1 + xlo, 0), IMG_W - 1);
    const int xhi_abs = min(max(x1 + xhi, 0), IMG_W - 1);

    Coords c;
    c.fx = sx - (float)xlo;
    c.fy = sy - (float)ylo;
    c.b00 = ((size_t)ylo_abs * IMG_W + xlo_abs) * IMG_C + coff;
    c.b01 = ((size_t)ylo_abs * IMG_W + xhi_abs) * IMG_C + coff;
    c.b10 = ((size_t)yhi_abs * IMG_W + xlo_abs) * IMG_C + coff;
    c.b11 = ((size_t)yhi_abs * IMG_W + xhi_abs) * IMG_C + coff;
    return c;
}

__device__ __forceinline__ float4 lerp2d(float4 v00, float4 v01, float4 v10,
                                         float4 v11, float fx, float fy) {
    const float gx = 1.0f - fx;
    const float gy = 1.0f - fy;
    float4 o;
    o.x = (v00.x * gx + v01.x * fx) * gy + (v10.x * gx + v11.x * fx) * fy;
    o.y = (v00.y * gx + v01.y * fx) * gy + (v10.y * gx + v11.y * fx) * fy;
    o.z = (v00.z * gx + v01.z * fx) * gy + (v10.z * gx + v11.z * fx) * fy;
    o.w = (v00.w * gx + v01.w * fx) * gy + (v10.w * gx + v11.w * fx) * fy;
    return o;
}

__global__ __launch_bounds__(256) void roi_pool_kernel(
    const float* __restrict__ img,
    const float* __restrict__ rois,
    float* __restrict__ out)
{
    const int total = HALF * 32;
    int idx = blockIdx.x * blockDim.x + threadIdx.x;
    if (idx >= total) return;

    const int c4   = idx & 31;       // float4 index within channels
    const int p0   = idx >> 5;       // first position
    const int p1   = p0 + HALF;      // second position
    const int coff = c4 * 4;

    const Coords ca = pos_coords(rois, p0, coff);
    const Coords cb = pos_coords(rois, p1, coff);

    // Issue all 8 loads before any use (MLP).
    const float4 a00 = *(const float4*)(img + ca.b00);
    const float4 a01 = *(const float4*)(img + ca.b01);
    const float4 a10 = *(const float4*)(img + ca.b10);
    const float4 a11 = *(const float4*)(img + ca.b11);
    const float4 d00 = *(const float4*)(img + cb.b00);
    const float4 d01 = *(const float4*)(img + cb.b01);
    const float4 d10 = *(const float4*)(img + cb.b10);
    const float4 d11 = *(const float4*)(img + cb.b11);

    *(float4*)(out + (size_t)p0 * IMG_C + coff) =
        lerp2d(a00, a01, a10, a11, ca.fx, ca.fy);
    *(float4*)(out + (size_t)p1 * IMG_C + coff) =
        lerp2d(d00, d01, d10, d11, cb.fx, cb.fy);
}

extern "C" void kernel_launch(void* const* d_in, const int* in_sizes, int n_in,
                              void* d_out, int out_size, void* d_ws, size_t ws_size,
                              hipStream_t stream) {
    const float* img  = (const float*)d_in[0];
    const float* rois = (const float*)d_in[1];
    float* out = (float*)d_out;

    const int total = HALF * 32;            // 401408 threads
    const int block = 256;
    const int grid  = (total + block - 1) / block;  // 1568 blocks
    roi_pool_kernel<<<grid, block, 0, stream>>>(img, rois, out);
}

// Round 3
// 15.495 us; speedup vs baseline: 1.0268x; 1.0106x over previous
//
#include <hip/hip_runtime.h>

// ROI bilinear pooling: img (1,1024,1024,128) f32, rois (1,512,4) f32 [x1,y1,w,h]
// out (1,512,7,7,128) f32.
// TF1 resize_images bilinear align_corners=False: src = dst * size/POOL.
//
// Layout: one WAVE (64 lanes) = one output row (roi, py); lane l holds
// channels {2l, 2l+1} as float2. Every global load instruction is exactly one
// contiguous 512 B segment (a whole pixel's channel vector), a wave's loads
// touch only 2 image rows in ascending-x order, and coord math is computed
// once per row (not per channel slice).

#define POOL 7
#define NUM_ROIS 512
#define IMG_H 1024
#define IMG_W 1024
#define IMG_C 128
#define NROWS (NUM_ROIS * POOL)   // 3584 waves

__device__ __forceinline__ float2 lerp2(float2 v00, float2 v01, float2 v10,
                                        float2 v11, float fx, float fy) {
    const float gx = 1.0f - fx;
    const float gy = 1.0f - fy;
    float2 o;
    o.x = (v00.x * gx + v01.x * fx) * gy + (v10.x * gx + v11.x * fx) * fy;
    o.y = (v00.y * gx + v01.y * fx) * gy + (v10.y * gx + v11.y * fx) * fy;
    return o;
}

__global__ __launch_bounds__(256) void roi_pool_kernel(
    const float* __restrict__ img,
    const float* __restrict__ rois,
    float* __restrict__ out)
{
    const int gtid = blockIdx.x * blockDim.x + threadIdx.x;
    const int wid  = gtid >> 6;      // wave id = roi*7 + py
    const int lane = gtid & 63;

    const int py  = wid % POOL;
    const int roi = wid / POOL;

    const float* r = rois + (size_t)roi * 4;
    const int x1 = (int)r[0];
    const int y1 = (int)r[1];
    const int w  = (int)r[2];
    const int h  = (int)r[3];

    // --- y axis (computed once per row; src >= 0 so trunc == floor) ---
    const float scy = (float)h / 7.0f;
    const float sy  = (float)py * scy;
    int ylo = (int)sy;
    ylo = min(ylo, h - 1);
    const int yhi = min(ylo + 1, h - 1);
    const float fy = sy - (float)ylo;
    const int ylo_abs = min(max(y1 + ylo, 0), IMG_H - 1);
    const int yhi_abs = min(max(y1 + yhi, 0), IMG_H - 1);

    const int coff = lane * 2;   // channel offset for this lane's float2
    const float* rowlo = img + (size_t)ylo_abs * IMG_W * IMG_C + coff;
    const float* rowhi = img + (size_t)yhi_abs * IMG_W * IMG_C + coff;
    float* orow = out + (size_t)wid * POOL * IMG_C + coff;

    const float scx = (float)w / 7.0f;

    #pragma unroll
    for (int px = 0; px < POOL; ++px) {
        const float sx = (float)px * scx;
        int xlo = (int)sx;
        xlo = min(xlo, w - 1);
        const int xhi = min(xlo + 1, w - 1);
        const float fx = sx - (float)xlo;
        const int xlo_abs = min(max(x1 + xlo, 0), IMG_W - 1);
        const int xhi_abs = min(max(x1 + xhi, 0), IMG_W - 1);

        const float2 v00 = *(const float2*)(rowlo + (size_t)xlo_abs * IMG_C);
        const float2 v01 = *(const float2*)(rowlo + (size_t)xhi_abs * IMG_C);
        const float2 v10 = *(const float2*)(rowhi + (size_t)xlo_abs * IMG_C);
        const float2 v11 = *(const float2*)(rowhi + (size_t)xhi_abs * IMG_C);

        *(float2*)(orow + (size_t)px * IMG_C) = lerp2(v00, v01, v10, v11, fx, fy);
    }
}

extern "C" void kernel_launch(void* const* d_in, const int* in_sizes, int n_in,
                              void* d_out, int out_size, void* d_ws, size_t ws_size,
                              hipStream_t stream) {
    const float* img  = (const float*)d_in[0];
    const float* rois = (const float*)d_in[1];
    float* out = (float*)d_out;

    const int total = NROWS * 64;   // 229376 threads, one wave per output row
    const int block = 256;
    const int grid  = total / block;  // 896 blocks, exact
    roi_pool_kernel<<<grid, block, 0, stream>>>(img, rois, out);
}